// Round 8
// baseline (441.658 us; speedup 1.0000x reference)
//
#include <hip/hip_runtime.h>
#include <hip/hip_bf16.h>

// GraphConv x2 via dst-sorted CSR gather (no float atomics):
//   gather1: aggm = mean_e w*x[src]
//   nodeA:   h  = sigmoid(aggm@Wrel1^T + b1 + x@Wroot1^T)   (LDS weights)
//   nodeB:   hr = h@Wrel2^T ; hro = h@Wroot2^T + b2          (LDS weights)
//   gather2: out = mean_e w*hr[src] + hro
// nodeA/B weights live in LDS as [c][f] float4 (lane-consecutive b128 reads,
// conflict-free); 4 nodes/iter amortize each weight read over 32 FMAs.
// Register-pinning attempts failed (LLVM remat/scratch, VGPR stuck at 72).

#define NF 64

// ---------------- dtype detection (int64 vs int32 edge_index) ---------------
__global__ void detect_i64(const unsigned* __restrict__ raw, int* __restrict__ flag, int E) {
    __shared__ unsigned red[256];
    unsigned v = 0;
    int lim = (E < 4096) ? E : 4096;
    for (int i = threadIdx.x; i < lim; i += 256) v |= raw[2 * i + 1];
    red[threadIdx.x] = v;
    __syncthreads();
    for (int s = 128; s > 0; s >>= 1) {
        if (threadIdx.x < s) red[threadIdx.x] |= red[threadIdx.x + s];
        __syncthreads();
    }
    if (threadIdx.x == 0) *flag = (red[0] == 0) ? 1 : 0;  // high dwords zero => int64
}

// ---------------- histogram of dst + materialize dst32 -----------------------
__global__ __launch_bounds__(256) void hist(const void* __restrict__ raw,
                                            const int* __restrict__ flag,
                                            int* __restrict__ deg,
                                            int* __restrict__ dst32, int E) {
    int e = blockIdx.x * blockDim.x + threadIdx.x;
    if (e >= E) return;
    int d;
    if (*flag) d = (int)__builtin_nontemporal_load(((const long long*)raw) + E + e);
    else       d = __builtin_nontemporal_load(((const int*)raw) + E + e);
    dst32[e] = d;
    atomicAdd(&deg[d], 1);
}

// ---------------- exclusive scan (3 kernels) ---------------------------------
__global__ __launch_bounds__(1024) void scan_k1(const int* __restrict__ deg,
                                                int* __restrict__ base,
                                                int* __restrict__ bsums, int N) {
    __shared__ int tmp[1024];
    int tid = threadIdx.x;
    int i = blockIdx.x * 1024 + tid;
    int v = (i < N) ? deg[i] : 0;
    tmp[tid] = v;
    __syncthreads();
    for (int off = 1; off < 1024; off <<= 1) {
        int t = (tid >= off) ? tmp[tid - off] : 0;
        __syncthreads();
        tmp[tid] += t;
        __syncthreads();
    }
    if (i < N) base[i] = tmp[tid] - v;
    if (tid == 1023) bsums[blockIdx.x] = tmp[tid];
}

__global__ __launch_bounds__(256) void scan_k2(int* __restrict__ bsums, int nb) {
    __shared__ int tmp[256];
    int tid = threadIdx.x;
    int v = (tid < nb) ? bsums[tid] : 0;
    tmp[tid] = v;
    __syncthreads();
    for (int off = 1; off < 256; off <<= 1) {
        int t = (tid >= off) ? tmp[tid - off] : 0;
        __syncthreads();
        tmp[tid] += t;
        __syncthreads();
    }
    if (tid < nb) bsums[tid] = tmp[tid] - v;
}

__global__ __launch_bounds__(1024) void scan_k3(int* __restrict__ base,
                                                const int* __restrict__ bsums,
                                                int* __restrict__ cursor, int N) {
    int i = blockIdx.x * 1024 + threadIdx.x;
    if (i >= N) return;
    int b = base[i] + bsums[blockIdx.x];
    base[i] = b;
    cursor[i] = b;
}

// ---------------- fill CSR: 7 dst-range passes in one launch ------------------
__global__ __launch_bounds__(256) void fill_pass(
    const void* __restrict__ raw, const int* __restrict__ flag,
    const float* __restrict__ ea, const int* __restrict__ dst32,
    int* __restrict__ cursor, int2* __restrict__ csr, int E, int bpp)
{
    int pass = blockIdx.x / bpp;
    int e = (blockIdx.x - pass * bpp) * 256 + threadIdx.x;
    if (e >= E) return;
    int d = dst32[e];
    if ((d >> 14) != pass) return;
    int s;
    if (*flag) s = (int)((const long long*)raw)[e];
    else       s = ((const int*)raw)[e];
    float w = ea[e];
    int slot = atomicAdd(&cursor[d], 1);
    csr[slot] = make_int2(s, __float_as_int(w));
}

// ---------------- gather1: aggm[n] = (sum_e w*x[src])/max(deg,1) -------------
__global__ __launch_bounds__(256) void gather1(
    const float* __restrict__ x, const int2* __restrict__ csr,
    const int* __restrict__ base, const int* __restrict__ deg,
    float* __restrict__ aggm, int N)
{
    int lane = threadIdx.x & 63;
    int wid = blockIdx.x * 4 + (threadIdx.x >> 6);
    int stride = gridDim.x * 4;
    for (int n = wid; n < N; n += stride) {
        int b = __builtin_amdgcn_readfirstlane(base[n]);
        int dg = __builtin_amdgcn_readfirstlane(deg[n]);
        float acc0 = 0.f, acc1 = 0.f, acc2 = 0.f, acc3 = 0.f;
        int i = b, e = b + dg;
        for (; i + 8 <= e; i += 8) {
            int2 r0 = csr[i], r1 = csr[i + 1], r2 = csr[i + 2], r3 = csr[i + 3];
            int2 r4 = csr[i + 4], r5 = csr[i + 5], r6 = csr[i + 6], r7 = csr[i + 7];
            float v0 = x[(size_t)r0.x * 64 + lane];
            float v1 = x[(size_t)r1.x * 64 + lane];
            float v2 = x[(size_t)r2.x * 64 + lane];
            float v3 = x[(size_t)r3.x * 64 + lane];
            float v4 = x[(size_t)r4.x * 64 + lane];
            float v5 = x[(size_t)r5.x * 64 + lane];
            float v6 = x[(size_t)r6.x * 64 + lane];
            float v7 = x[(size_t)r7.x * 64 + lane];
            acc0 = fmaf(__int_as_float(r0.y), v0, acc0);
            acc1 = fmaf(__int_as_float(r1.y), v1, acc1);
            acc2 = fmaf(__int_as_float(r2.y), v2, acc2);
            acc3 = fmaf(__int_as_float(r3.y), v3, acc3);
            acc0 = fmaf(__int_as_float(r4.y), v4, acc0);
            acc1 = fmaf(__int_as_float(r5.y), v5, acc1);
            acc2 = fmaf(__int_as_float(r6.y), v6, acc2);
            acc3 = fmaf(__int_as_float(r7.y), v7, acc3);
        }
        for (; i + 4 <= e; i += 4) {
            int2 r0 = csr[i], r1 = csr[i + 1], r2 = csr[i + 2], r3 = csr[i + 3];
            acc0 = fmaf(__int_as_float(r0.y), x[(size_t)r0.x * 64 + lane], acc0);
            acc1 = fmaf(__int_as_float(r1.y), x[(size_t)r1.x * 64 + lane], acc1);
            acc2 = fmaf(__int_as_float(r2.y), x[(size_t)r2.x * 64 + lane], acc2);
            acc3 = fmaf(__int_as_float(r3.y), x[(size_t)r3.x * 64 + lane], acc3);
        }
        for (; i < e; ++i) {
            int2 r = csr[i];
            acc0 = fmaf(__int_as_float(r.y), x[(size_t)r.x * 64 + lane], acc0);
        }
        float inv = 1.0f / fmaxf((float)dg, 1.0f);
        aggm[(size_t)n * 64 + lane] = ((acc0 + acc1) + (acc2 + acc3)) * inv;
    }
}

// ---------------- nodeA: h = sigmoid(aggm@Wrel1^T + b1 + x@Wroot1^T) ---------
// Weights in LDS as [c][f] float4: lane f reads wlds[c][f] -> consecutive
// lanes read consecutive 16B (standard conflict-free b128). 4 nodes/iter:
// per c = 2 ds_b128 (24cy) + 32 FMA (64cy) -> VALU-bound.
__global__ __launch_bounds__(256) void nodeA(
    const float* __restrict__ x, const float* __restrict__ aggm,
    const float* __restrict__ Wrel1, const float* __restrict__ brel1,
    const float* __restrict__ Wroot1, float* __restrict__ h, int N)
{
    __shared__ float4 lwr[16][64];
    __shared__ float4 lwo[16][64];
    int t = threadIdx.x;
    for (int i = t; i < 1024; i += 256) {
        int f = i >> 4, c = i & 15;                 // coalesced global read
        lwr[c][f] = *(const float4*)(Wrel1 + (size_t)f * 64 + 4 * c);
        lwo[c][f] = *(const float4*)(Wroot1 + (size_t)f * 64 + 4 * c);
    }
    __syncthreads();
    int lane = t & 63;
    float bias = brel1[lane];
    int wid = blockIdx.x * 4 + (t >> 6);
    int stride = gridDim.x * 4;
    for (int g = wid * 4; g < N; g += stride * 4) {
        int rem = N - g;
        int n0 = __builtin_amdgcn_readfirstlane(g);
        int n1 = __builtin_amdgcn_readfirstlane(rem > 1 ? g + 1 : g);
        int n2 = __builtin_amdgcn_readfirstlane(rem > 2 ? g + 2 : g);
        int n3 = __builtin_amdgcn_readfirstlane(rem > 3 ? g + 3 : g);
        const float* a0 = aggm + (size_t)n0 * 64; const float* x0 = x + (size_t)n0 * 64;
        const float* a1 = aggm + (size_t)n1 * 64; const float* x1 = x + (size_t)n1 * 64;
        const float* a2 = aggm + (size_t)n2 * 64; const float* x2 = x + (size_t)n2 * 64;
        const float* a3 = aggm + (size_t)n3 * 64; const float* x3 = x + (size_t)n3 * 64;
        float r0 = bias, r1 = bias, r2 = bias, r3 = bias;
        float o0 = 0.f, o1 = 0.f, o2 = 0.f, o3 = 0.f;
#pragma unroll
        for (int c = 0; c < 16; ++c) {
            float4 wr = lwr[c][lane];
            float4 wo = lwo[c][lane];
            float4 A0 = *(const float4*)(a0 + 4 * c);
            float4 A1 = *(const float4*)(a1 + 4 * c);
            float4 A2 = *(const float4*)(a2 + 4 * c);
            float4 A3 = *(const float4*)(a3 + 4 * c);
            r0 = fmaf(wr.x, A0.x, r0); r1 = fmaf(wr.x, A1.x, r1);
            r2 = fmaf(wr.x, A2.x, r2); r3 = fmaf(wr.x, A3.x, r3);
            r0 = fmaf(wr.y, A0.y, r0); r1 = fmaf(wr.y, A1.y, r1);
            r2 = fmaf(wr.y, A2.y, r2); r3 = fmaf(wr.y, A3.y, r3);
            r0 = fmaf(wr.z, A0.z, r0); r1 = fmaf(wr.z, A1.z, r1);
            r2 = fmaf(wr.z, A2.z, r2); r3 = fmaf(wr.z, A3.z, r3);
            r0 = fmaf(wr.w, A0.w, r0); r1 = fmaf(wr.w, A1.w, r1);
            r2 = fmaf(wr.w, A2.w, r2); r3 = fmaf(wr.w, A3.w, r3);
            float4 X0 = *(const float4*)(x0 + 4 * c);
            float4 X1 = *(const float4*)(x1 + 4 * c);
            float4 X2 = *(const float4*)(x2 + 4 * c);
            float4 X3 = *(const float4*)(x3 + 4 * c);
            o0 = fmaf(wo.x, X0.x, o0); o1 = fmaf(wo.x, X1.x, o1);
            o2 = fmaf(wo.x, X2.x, o2); o3 = fmaf(wo.x, X3.x, o3);
            o0 = fmaf(wo.y, X0.y, o0); o1 = fmaf(wo.y, X1.y, o1);
            o2 = fmaf(wo.y, X2.y, o2); o3 = fmaf(wo.y, X3.y, o3);
            o0 = fmaf(wo.z, X0.z, o0); o1 = fmaf(wo.z, X1.z, o1);
            o2 = fmaf(wo.z, X2.z, o2); o3 = fmaf(wo.z, X3.z, o3);
            o0 = fmaf(wo.w, X0.w, o0); o1 = fmaf(wo.w, X1.w, o1);
            o2 = fmaf(wo.w, X2.w, o2); o3 = fmaf(wo.w, X3.w, o3);
        }
        h[(size_t)n0 * 64 + lane] = 1.0f / (1.0f + __expf(-(r0 + o0)));
        if (rem > 1) h[(size_t)n1 * 64 + lane] = 1.0f / (1.0f + __expf(-(r1 + o1)));
        if (rem > 2) h[(size_t)n2 * 64 + lane] = 1.0f / (1.0f + __expf(-(r2 + o2)));
        if (rem > 3) h[(size_t)n3 * 64 + lane] = 1.0f / (1.0f + __expf(-(r3 + o3)));
    }
}

// ---------------- nodeB: hr = h@Wrel2^T ; hro = h@Wroot2^T + b2 --------------
// Combined weight tile in LDS: rows j<32 = Wrel2[j], rows >=32 = Wroot2[j-32].
__global__ __launch_bounds__(256) void nodeB(
    const float* __restrict__ h, const float* __restrict__ Wrel2,
    const float* __restrict__ brel2, const float* __restrict__ Wroot2,
    float* __restrict__ hr, float* __restrict__ hro, int N)
{
    __shared__ float4 lw[16][64];
    int t = threadIdx.x;
    for (int i = t; i < 1024; i += 256) {
        int f = i >> 4, c = i & 15;
        const float* src = (f < 32) ? (Wrel2 + (size_t)f * 64) : (Wroot2 + (size_t)(f - 32) * 64);
        lw[c][f] = *(const float4*)(src + 4 * c);
    }
    __syncthreads();
    int lane = t & 63;
    int j = lane & 31;
    bool isRel = lane < 32;
    float bias = isRel ? 0.f : brel2[j];
    float* dstbuf = isRel ? hr : hro;
    int wid = blockIdx.x * 4 + (t >> 6);
    int stride = gridDim.x * 4;
    for (int g = wid * 4; g < N; g += stride * 4) {
        int rem = N - g;
        int n0 = __builtin_amdgcn_readfirstlane(g);
        int n1 = __builtin_amdgcn_readfirstlane(rem > 1 ? g + 1 : g);
        int n2 = __builtin_amdgcn_readfirstlane(rem > 2 ? g + 2 : g);
        int n3 = __builtin_amdgcn_readfirstlane(rem > 3 ? g + 3 : g);
        const float* h0 = h + (size_t)n0 * 64;
        const float* h1 = h + (size_t)n1 * 64;
        const float* h2 = h + (size_t)n2 * 64;
        const float* h3 = h + (size_t)n3 * 64;
        float c0 = bias, c1 = bias, c2 = bias, c3 = bias;
#pragma unroll
        for (int c = 0; c < 16; ++c) {
            float4 w = lw[c][lane];
            float4 V0 = *(const float4*)(h0 + 4 * c);
            float4 V1 = *(const float4*)(h1 + 4 * c);
            float4 V2 = *(const float4*)(h2 + 4 * c);
            float4 V3 = *(const float4*)(h3 + 4 * c);
            c0 = fmaf(w.x, V0.x, c0); c1 = fmaf(w.x, V1.x, c1);
            c2 = fmaf(w.x, V2.x, c2); c3 = fmaf(w.x, V3.x, c3);
            c0 = fmaf(w.y, V0.y, c0); c1 = fmaf(w.y, V1.y, c1);
            c2 = fmaf(w.y, V2.y, c2); c3 = fmaf(w.y, V3.y, c3);
            c0 = fmaf(w.z, V0.z, c0); c1 = fmaf(w.z, V1.z, c1);
            c2 = fmaf(w.z, V2.z, c2); c3 = fmaf(w.z, V3.z, c3);
            c0 = fmaf(w.w, V0.w, c0); c1 = fmaf(w.w, V1.w, c1);
            c2 = fmaf(w.w, V2.w, c2); c3 = fmaf(w.w, V3.w, c3);
        }
        dstbuf[(size_t)n0 * 32 + j] = c0;
        if (rem > 1) dstbuf[(size_t)n1 * 32 + j] = c1;
        if (rem > 2) dstbuf[(size_t)n2 * 32 + j] = c2;
        if (rem > 3) dstbuf[(size_t)n3 * 32 + j] = c3;
    }
}

// ---------------- gather2 + epilogue: out = agg2/deg + hro -------------------
__global__ __launch_bounds__(256) void gather2(
    const float* __restrict__ hr, const float* __restrict__ hro,
    const int2* __restrict__ csr, const int* __restrict__ base,
    const int* __restrict__ deg, float* __restrict__ out, int N)
{
    int lane = threadIdx.x & 63;
    int j = lane & 31, half = lane >> 5;
    int wid = blockIdx.x * 4 + (threadIdx.x >> 6);
    int stride = gridDim.x * 4;
    for (int n = wid; n < N; n += stride) {
        int b = __builtin_amdgcn_readfirstlane(base[n]);
        int dg = __builtin_amdgcn_readfirstlane(deg[n]);
        float a0 = 0.f, a1 = 0.f, a2 = 0.f, a3 = 0.f;
        int i = b + half, e = b + dg;
        for (; i + 8 <= e + half; i += 8) {
            int2 r0 = csr[i], r1 = csr[i + 2], r2 = csr[i + 4], r3 = csr[i + 6];
            a0 = fmaf(__int_as_float(r0.y), hr[(size_t)r0.x * 32 + j], a0);
            a1 = fmaf(__int_as_float(r1.y), hr[(size_t)r1.x * 32 + j], a1);
            a2 = fmaf(__int_as_float(r2.y), hr[(size_t)r2.x * 32 + j], a2);
            a3 = fmaf(__int_as_float(r3.y), hr[(size_t)r3.x * 32 + j], a3);
        }
        for (; i < e; i += 2) {
            int2 r = csr[i];
            a0 = fmaf(__int_as_float(r.y), hr[(size_t)r.x * 32 + j], a0);
        }
        float acc = (a0 + a1) + (a2 + a3);
        acc += __shfl_xor(acc, 32);
        if (half == 0) {
            float inv = 1.0f / fmaxf((float)dg, 1.0f);
            out[(size_t)n * 32 + j] = acc * inv + hro[(size_t)n * 32 + j];
        }
    }
}

extern "C" void kernel_launch(void* const* d_in, const int* in_sizes, int n_in,
                              void* d_out, int out_size, void* d_ws, size_t ws_size,
                              hipStream_t stream) {
    const float* x      = (const float*)d_in[0];
    const void*  ei_raw = d_in[1];
    const float* ea     = (const float*)d_in[2];
    const float* Wrel1  = (const float*)d_in[3];
    const float* brel1  = (const float*)d_in[4];
    const float* Wroot1 = (const float*)d_in[5];
    const float* Wrel2  = (const float*)d_in[6];
    const float* brel2  = (const float*)d_in[7];
    const float* Wroot2 = (const float*)d_in[8];
    float* out = (float*)d_out;

    const int N = in_sizes[0] / NF;     // 100000
    const int E = in_sizes[2];          // 1000000

    // workspace layout
    int2*  csr    = (int2*)d_ws;                    // E (8 MB)
    int*   deg    = (int*)(csr + E);                // N
    int*   base   = deg + N;                        // N
    int*   cursor = base + N;                       // N
    int*   bsums  = cursor + N;                     // 256
    int*   flag   = bsums + 256;                    // 1 (+3 pad)
    int*   dst32  = flag + 4;                       // E (4 MB)
    float* aggm   = (float*)(dst32 + E);            // N*64 ; reused as hr|hro
    float* h      = aggm + (size_t)N * 64;          // N*64
    float* hr     = aggm;                           // N*32 (aggm dead after nodeA)
    float* hro    = aggm + (size_t)N * 32;          // N*32

    const int nb1 = (N + 1023) / 1024;
    const int bpp = (E + 255) / 256;                // blocks per pass
    const int npass = (N + 16383) >> 14;            // 7 for N=100000

    hipMemsetAsync(deg, 0, (size_t)N * sizeof(int), stream);
    detect_i64<<<1, 256, 0, stream>>>((const unsigned*)ei_raw, flag, E);
    hist<<<bpp, 256, 0, stream>>>(ei_raw, flag, deg, dst32, E);
    scan_k1<<<nb1, 1024, 0, stream>>>(deg, base, bsums, N);
    scan_k2<<<1, 256, 0, stream>>>(bsums, nb1);
    scan_k3<<<nb1, 1024, 0, stream>>>(base, bsums, cursor, N);
    fill_pass<<<npass * bpp, 256, 0, stream>>>(ei_raw, flag, ea, dst32, cursor, csr, E, bpp);

    gather1<<<2048, 256, 0, stream>>>(x, csr, base, deg, aggm, N);
    nodeA<<<2048, 256, 0, stream>>>(x, aggm, Wrel1, brel1, Wroot1, h, N);
    nodeB<<<2048, 256, 0, stream>>>(h, Wrel2, brel2, Wroot2, hr, hro, N);
    gather2<<<2048, 256, 0, stream>>>(hr, hro, csr, base, deg, out, N);
}

// Round 9
// 333.884 us; speedup vs baseline: 1.3228x; 1.3228x over previous
//
#include <hip/hip_runtime.h>
#include <hip/hip_bf16.h>

// GraphConv x2 via dst-sorted CSR gather (no float atomics):
//   gather1:    aggm = mean_e w*x[src]
//   node_fused: tiled SGEMM (64-node tile, 4x4 micro-tiles):
//               h   = sigmoid(aggm@Wrel1^T + b1 + x@Wroot1^T)  (h stays in LDS)
//               hr  = h@Wrel2^T ; hro = h@Wroot2^T + b2
//   gather2:    out = mean_e w*hr[src] + hro
// Lesson from rounds 3-8: warp-per-node with lane=feature is structurally
// wrong (per-lane weight rows -> remat'ed L1 gathers or AGPR spills; broadcast
// activations -> serialized lgkmcnt chains). Tiled GEMM fixes both.

#define NF 64
#define WS 68   // padded LDS row stride (floats): 16B-aligned rows, 2-way max

// ---------------- dtype detection (int64 vs int32 edge_index) ---------------
__global__ void detect_i64(const unsigned* __restrict__ raw, int* __restrict__ flag, int E) {
    __shared__ unsigned red[256];
    unsigned v = 0;
    int lim = (E < 4096) ? E : 4096;
    for (int i = threadIdx.x; i < lim; i += 256) v |= raw[2 * i + 1];
    red[threadIdx.x] = v;
    __syncthreads();
    for (int s = 128; s > 0; s >>= 1) {
        if (threadIdx.x < s) red[threadIdx.x] |= red[threadIdx.x + s];
        __syncthreads();
    }
    if (threadIdx.x == 0) *flag = (red[0] == 0) ? 1 : 0;  // high dwords zero => int64
}

// ---------------- histogram of dst + materialize dst32 -----------------------
__global__ __launch_bounds__(256) void hist(const void* __restrict__ raw,
                                            const int* __restrict__ flag,
                                            int* __restrict__ deg,
                                            int* __restrict__ dst32, int E) {
    int e = blockIdx.x * blockDim.x + threadIdx.x;
    if (e >= E) return;
    int d;
    if (*flag) d = (int)__builtin_nontemporal_load(((const long long*)raw) + E + e);
    else       d = __builtin_nontemporal_load(((const int*)raw) + E + e);
    dst32[e] = d;
    atomicAdd(&deg[d], 1);
}

// ---------------- exclusive scan (3 kernels) ---------------------------------
__global__ __launch_bounds__(1024) void scan_k1(const int* __restrict__ deg,
                                                int* __restrict__ base,
                                                int* __restrict__ bsums, int N) {
    __shared__ int tmp[1024];
    int tid = threadIdx.x;
    int i = blockIdx.x * 1024 + tid;
    int v = (i < N) ? deg[i] : 0;
    tmp[tid] = v;
    __syncthreads();
    for (int off = 1; off < 1024; off <<= 1) {
        int t = (tid >= off) ? tmp[tid - off] : 0;
        __syncthreads();
        tmp[tid] += t;
        __syncthreads();
    }
    if (i < N) base[i] = tmp[tid] - v;
    if (tid == 1023) bsums[blockIdx.x] = tmp[tid];
}

__global__ __launch_bounds__(256) void scan_k2(int* __restrict__ bsums, int nb) {
    __shared__ int tmp[256];
    int tid = threadIdx.x;
    int v = (tid < nb) ? bsums[tid] : 0;
    tmp[tid] = v;
    __syncthreads();
    for (int off = 1; off < 256; off <<= 1) {
        int t = (tid >= off) ? tmp[tid - off] : 0;
        __syncthreads();
        tmp[tid] += t;
        __syncthreads();
    }
    if (tid < nb) bsums[tid] = tmp[tid] - v;
}

__global__ __launch_bounds__(1024) void scan_k3(int* __restrict__ base,
                                                const int* __restrict__ bsums,
                                                int* __restrict__ cursor, int N) {
    int i = blockIdx.x * 1024 + threadIdx.x;
    if (i >= N) return;
    int b = base[i] + bsums[blockIdx.x];
    base[i] = b;
    cursor[i] = b;
}

// ---------------- fill CSR slots (single pass, reads cached dst32) -----------
__global__ __launch_bounds__(256) void fill_csr(const void* __restrict__ raw,
                                                const int* __restrict__ flag,
                                                const float* __restrict__ ea,
                                                const int* __restrict__ dst32,
                                                int* __restrict__ cursor,
                                                int2* __restrict__ csr, int E) {
    int e = blockIdx.x * blockDim.x + threadIdx.x;
    if (e >= E) return;
    int d = dst32[e];
    int s;
    if (*flag) s = (int)__builtin_nontemporal_load(((const long long*)raw) + e);
    else       s = __builtin_nontemporal_load(((const int*)raw) + e);
    float w = __builtin_nontemporal_load(ea + e);
    int slot = atomicAdd(&cursor[d], 1);
    csr[slot] = make_int2(s, __float_as_int(w));
}

// ---------------- gather1: aggm[n] = (sum_e w*x[src])/max(deg,1) -------------
__global__ __launch_bounds__(256) void gather1(
    const float* __restrict__ x, const int2* __restrict__ csr,
    const int* __restrict__ base, const int* __restrict__ deg,
    float* __restrict__ aggm, int N)
{
    int lane = threadIdx.x & 63;
    int wid = blockIdx.x * 4 + (threadIdx.x >> 6);
    int stride = gridDim.x * 4;
    for (int n = wid; n < N; n += stride) {
        int b = __builtin_amdgcn_readfirstlane(base[n]);
        int dg = __builtin_amdgcn_readfirstlane(deg[n]);
        float acc0 = 0.f, acc1 = 0.f, acc2 = 0.f, acc3 = 0.f;
        int i = b, e = b + dg;
        for (; i + 8 <= e; i += 8) {
            int2 r0 = csr[i], r1 = csr[i + 1], r2 = csr[i + 2], r3 = csr[i + 3];
            int2 r4 = csr[i + 4], r5 = csr[i + 5], r6 = csr[i + 6], r7 = csr[i + 7];
            float v0 = x[(size_t)r0.x * 64 + lane];
            float v1 = x[(size_t)r1.x * 64 + lane];
            float v2 = x[(size_t)r2.x * 64 + lane];
            float v3 = x[(size_t)r3.x * 64 + lane];
            float v4 = x[(size_t)r4.x * 64 + lane];
            float v5 = x[(size_t)r5.x * 64 + lane];
            float v6 = x[(size_t)r6.x * 64 + lane];
            float v7 = x[(size_t)r7.x * 64 + lane];
            acc0 = fmaf(__int_as_float(r0.y), v0, acc0);
            acc1 = fmaf(__int_as_float(r1.y), v1, acc1);
            acc2 = fmaf(__int_as_float(r2.y), v2, acc2);
            acc3 = fmaf(__int_as_float(r3.y), v3, acc3);
            acc0 = fmaf(__int_as_float(r4.y), v4, acc0);
            acc1 = fmaf(__int_as_float(r5.y), v5, acc1);
            acc2 = fmaf(__int_as_float(r6.y), v6, acc2);
            acc3 = fmaf(__int_as_float(r7.y), v7, acc3);
        }
        for (; i + 4 <= e; i += 4) {
            int2 r0 = csr[i], r1 = csr[i + 1], r2 = csr[i + 2], r3 = csr[i + 3];
            acc0 = fmaf(__int_as_float(r0.y), x[(size_t)r0.x * 64 + lane], acc0);
            acc1 = fmaf(__int_as_float(r1.y), x[(size_t)r1.x * 64 + lane], acc1);
            acc2 = fmaf(__int_as_float(r2.y), x[(size_t)r2.x * 64 + lane], acc2);
            acc3 = fmaf(__int_as_float(r3.y), x[(size_t)r3.x * 64 + lane], acc3);
        }
        for (; i < e; ++i) {
            int2 r = csr[i];
            acc0 = fmaf(__int_as_float(r.y), x[(size_t)r.x * 64 + lane], acc0);
        }
        float inv = 1.0f / fmaxf((float)dg, 1.0f);
        aggm[(size_t)n * 64 + lane] = ((acc0 + acc1) + (acc2 + acc3)) * inv;
    }
}

// ---------------- node_fused: tiled SGEMM, 3 phases --------------------------
// Tile: 64 nodes x 64 features, 256 threads, thread (tm,tn) owns 4x4 outputs.
// A: act tile [m][k] stride 68; W: weight tile [k][f] stride 68 (transposed
// during staging). Per k4-step: 8 ds_read_b128 (64B/256B unique -> broadcast)
// + 64 FMA, immediate-offset addressing.
__global__ __launch_bounds__(256) void node_fused(
    const float* __restrict__ x, const float* __restrict__ aggm,
    const float* __restrict__ Wrel1, const float* __restrict__ brel1,
    const float* __restrict__ Wroot1,
    const float* __restrict__ Wrel2, const float* __restrict__ brel2,
    const float* __restrict__ Wroot2,
    float* __restrict__ hr, float* __restrict__ hro, int N)
{
    __shared__ float A[64 * WS];
    __shared__ float W[64 * WS];
    int t = threadIdx.x;
    int tn = t & 15, tm = t >> 4;
    int n0 = blockIdx.x * 64;
    int rem = N - n0;                      // < 64 only on last block

#define STAGE_A(SRC)                                                        \
    for (int idx = t; idx < 1024; idx += 256) {                             \
        int m = idx >> 4, c4 = idx & 15;                                    \
        int srcn = (m < rem) ? (n0 + m) : n0;                               \
        float4 v = *(const float4*)((SRC) + (size_t)srcn * 64 + c4 * 4);    \
        *(float4*)(&A[m * WS + c4 * 4]) = v;                                \
    }

#define STAGE_W(WG)                                                         \
    for (int idx = t; idx < 1024; idx += 256) {                             \
        int f = idx >> 4, c4 = idx & 15;                                    \
        float4 v = *(const float4*)((WG) + (size_t)f * 64 + c4 * 4);        \
        W[(c4 * 4 + 0) * WS + f] = v.x;                                     \
        W[(c4 * 4 + 1) * WS + f] = v.y;                                     \
        W[(c4 * 4 + 2) * WS + f] = v.z;                                     \
        W[(c4 * 4 + 3) * WS + f] = v.w;                                     \
    }

#define FMA_ROW(AV, ACC)                                                    \
    ACC.x = fmaf(AV.x, w0.x, ACC.x); ACC.y = fmaf(AV.x, w0.y, ACC.y);       \
    ACC.z = fmaf(AV.x, w0.z, ACC.z); ACC.w = fmaf(AV.x, w0.w, ACC.w);       \
    ACC.x = fmaf(AV.y, w1.x, ACC.x); ACC.y = fmaf(AV.y, w1.y, ACC.y);       \
    ACC.z = fmaf(AV.y, w1.z, ACC.z); ACC.w = fmaf(AV.y, w1.w, ACC.w);       \
    ACC.x = fmaf(AV.z, w2.x, ACC.x); ACC.y = fmaf(AV.z, w2.y, ACC.y);       \
    ACC.z = fmaf(AV.z, w2.z, ACC.z); ACC.w = fmaf(AV.z, w2.w, ACC.w);       \
    ACC.x = fmaf(AV.w, w3.x, ACC.x); ACC.y = fmaf(AV.w, w3.y, ACC.y);       \
    ACC.z = fmaf(AV.w, w3.z, ACC.z); ACC.w = fmaf(AV.w, w3.w, ACC.w);

#define COMPUTE()                                                           \
    _Pragma("unroll")                                                       \
    for (int k4 = 0; k4 < 16; ++k4) {                                       \
        float4 a0 = *(const float4*)(&A[(tm * 4 + 0) * WS + k4 * 4]);       \
        float4 a1 = *(const float4*)(&A[(tm * 4 + 1) * WS + k4 * 4]);       \
        float4 a2 = *(const float4*)(&A[(tm * 4 + 2) * WS + k4 * 4]);       \
        float4 a3 = *(const float4*)(&A[(tm * 4 + 3) * WS + k4 * 4]);       \
        float4 w0 = *(const float4*)(&W[(k4 * 4 + 0) * WS + tn * 4]);       \
        float4 w1 = *(const float4*)(&W[(k4 * 4 + 1) * WS + tn * 4]);       \
        float4 w2 = *(const float4*)(&W[(k4 * 4 + 2) * WS + tn * 4]);       \
        float4 w3 = *(const float4*)(&W[(k4 * 4 + 3) * WS + tn * 4]);       \
        FMA_ROW(a0, acc0) FMA_ROW(a1, acc1) FMA_ROW(a2, acc2) FMA_ROW(a3, acc3) \
    }

    // ---- phase 1: rel (act = aggm, W = Wrel1), acc init = b1 ----
    STAGE_W(Wrel1)
    STAGE_A(aggm)
    float4 bias1 = *(const float4*)(brel1 + tn * 4);
    float4 acc0 = bias1, acc1 = bias1, acc2 = bias1, acc3 = bias1;
    __syncthreads();
    COMPUTE()
    __syncthreads();

    // ---- phase 2: root (act = x, W = Wroot1), then sigmoid ----
    STAGE_W(Wroot1)
    STAGE_A(x)
    __syncthreads();
    COMPUTE()
    acc0.x = 1.f / (1.f + __expf(-acc0.x)); acc0.y = 1.f / (1.f + __expf(-acc0.y));
    acc0.z = 1.f / (1.f + __expf(-acc0.z)); acc0.w = 1.f / (1.f + __expf(-acc0.w));
    acc1.x = 1.f / (1.f + __expf(-acc1.x)); acc1.y = 1.f / (1.f + __expf(-acc1.y));
    acc1.z = 1.f / (1.f + __expf(-acc1.z)); acc1.w = 1.f / (1.f + __expf(-acc1.w));
    acc2.x = 1.f / (1.f + __expf(-acc2.x)); acc2.y = 1.f / (1.f + __expf(-acc2.y));
    acc2.z = 1.f / (1.f + __expf(-acc2.z)); acc2.w = 1.f / (1.f + __expf(-acc2.w));
    acc3.x = 1.f / (1.f + __expf(-acc3.x)); acc3.y = 1.f / (1.f + __expf(-acc3.y));
    acc3.z = 1.f / (1.f + __expf(-acc3.z)); acc3.w = 1.f / (1.f + __expf(-acc3.w));
    __syncthreads();   // all phase-2 reads of A and W done

    // ---- phase 3: h -> A (LDS only), W = [Wrel2 ; Wroot2] ----
    *(float4*)(&A[(tm * 4 + 0) * WS + tn * 4]) = acc0;
    *(float4*)(&A[(tm * 4 + 1) * WS + tn * 4]) = acc1;
    *(float4*)(&A[(tm * 4 + 2) * WS + tn * 4]) = acc2;
    *(float4*)(&A[(tm * 4 + 3) * WS + tn * 4]) = acc3;
    for (int idx = t; idx < 1024; idx += 256) {
        int f = idx >> 4, c4 = idx & 15;
        const float* src = (f < 32) ? (Wrel2 + (size_t)f * 64)
                                    : (Wroot2 + (size_t)(f - 32) * 64);
        float4 v = *(const float4*)(src + c4 * 4);
        W[(c4 * 4 + 0) * WS + f] = v.x;
        W[(c4 * 4 + 1) * WS + f] = v.y;
        W[(c4 * 4 + 2) * WS + f] = v.z;
        W[(c4 * 4 + 3) * WS + f] = v.w;
    }
    if (tn < 8) {
        acc0 = make_float4(0.f, 0.f, 0.f, 0.f);
    } else {
        acc0 = *(const float4*)(brel2 + (tn - 8) * 4);
    }
    acc1 = acc0; acc2 = acc0; acc3 = acc0;
    __syncthreads();
    COMPUTE()

    // ---- store hr (tn<8) / hro (tn>=8), [n*32 + j] ----
    float* dstb = (tn < 8) ? hr : hro;
    int jo = (tn & 7) * 4;
    if (tm * 4 + 0 < rem) *(float4*)(&dstb[(size_t)(n0 + tm * 4 + 0) * 32 + jo]) = acc0;
    if (tm * 4 + 1 < rem) *(float4*)(&dstb[(size_t)(n0 + tm * 4 + 1) * 32 + jo]) = acc1;
    if (tm * 4 + 2 < rem) *(float4*)(&dstb[(size_t)(n0 + tm * 4 + 2) * 32 + jo]) = acc2;
    if (tm * 4 + 3 < rem) *(float4*)(&dstb[(size_t)(n0 + tm * 4 + 3) * 32 + jo]) = acc3;
#undef STAGE_A
#undef STAGE_W
#undef FMA_ROW
#undef COMPUTE
}

// ---------------- gather2 + epilogue: out = agg2/deg + hro -------------------
__global__ __launch_bounds__(256) void gather2(
    const float* __restrict__ hr, const float* __restrict__ hro,
    const int2* __restrict__ csr, const int* __restrict__ base,
    const int* __restrict__ deg, float* __restrict__ out, int N)
{
    int lane = threadIdx.x & 63;
    int j = lane & 31, half = lane >> 5;
    int wid = blockIdx.x * 4 + (threadIdx.x >> 6);
    int stride = gridDim.x * 4;
    for (int n = wid; n < N; n += stride) {
        int b = __builtin_amdgcn_readfirstlane(base[n]);
        int dg = __builtin_amdgcn_readfirstlane(deg[n]);
        float a0 = 0.f, a1 = 0.f, a2 = 0.f, a3 = 0.f;
        int i = b + half, e = b + dg;
        for (; i + 8 <= e + half; i += 8) {
            int2 r0 = csr[i], r1 = csr[i + 2], r2 = csr[i + 4], r3 = csr[i + 6];
            a0 = fmaf(__int_as_float(r0.y), hr[(size_t)r0.x * 32 + j], a0);
            a1 = fmaf(__int_as_float(r1.y), hr[(size_t)r1.x * 32 + j], a1);
            a2 = fmaf(__int_as_float(r2.y), hr[(size_t)r2.x * 32 + j], a2);
            a3 = fmaf(__int_as_float(r3.y), hr[(size_t)r3.x * 32 + j], a3);
        }
        for (; i < e; i += 2) {
            int2 r = csr[i];
            a0 = fmaf(__int_as_float(r.y), hr[(size_t)r.x * 32 + j], a0);
        }
        float acc = (a0 + a1) + (a2 + a3);
        acc += __shfl_xor(acc, 32);
        if (half == 0) {
            float inv = 1.0f / fmaxf((float)dg, 1.0f);
            out[(size_t)n * 32 + j] = acc * inv + hro[(size_t)n * 32 + j];
        }
    }
}

extern "C" void kernel_launch(void* const* d_in, const int* in_sizes, int n_in,
                              void* d_out, int out_size, void* d_ws, size_t ws_size,
                              hipStream_t stream) {
    const float* x      = (const float*)d_in[0];
    const void*  ei_raw = d_in[1];
    const float* ea     = (const float*)d_in[2];
    const float* Wrel1  = (const float*)d_in[3];
    const float* brel1  = (const float*)d_in[4];
    const float* Wroot1 = (const float*)d_in[5];
    const float* Wrel2  = (const float*)d_in[6];
    const float* brel2  = (const float*)d_in[7];
    const float* Wroot2 = (const float*)d_in[8];
    float* out = (float*)d_out;

    const int N = in_sizes[0] / NF;     // 100000
    const int E = in_sizes[2];          // 1000000

    // workspace layout
    int2*  csr    = (int2*)d_ws;                    // E (8 MB)
    int*   deg    = (int*)(csr + E);                // N
    int*   base   = deg + N;                        // N
    int*   cursor = base + N;                       // N
    int*   bsums  = cursor + N;                     // 256
    int*   flag   = bsums + 256;                    // 1 (+3 pad)
    int*   dst32  = flag + 4;                       // E (4 MB)
    float* aggm   = (float*)(dst32 + E);            // N*64
    float* hr     = aggm + (size_t)N * 64;          // N*32
    float* hro    = hr + (size_t)N * 32;            // N*32

    const int nb1 = (N + 1023) / 1024;

    hipMemsetAsync(deg, 0, (size_t)N * sizeof(int), stream);
    detect_i64<<<1, 256, 0, stream>>>((const unsigned*)ei_raw, flag, E);
    hist<<<(E + 255) / 256, 256, 0, stream>>>(ei_raw, flag, deg, dst32, E);
    scan_k1<<<nb1, 1024, 0, stream>>>(deg, base, bsums, N);
    scan_k2<<<1, 256, 0, stream>>>(bsums, nb1);
    scan_k3<<<nb1, 1024, 0, stream>>>(base, bsums, cursor, N);
    fill_csr<<<(E + 255) / 256, 256, 0, stream>>>(ei_raw, flag, ea, dst32, cursor, csr, E);

    gather1<<<2048, 256, 0, stream>>>(x, csr, base, deg, aggm, N);
    node_fused<<<(N + 63) / 64, 256, 0, stream>>>(x, aggm, Wrel1, brel1, Wroot1,
                                                  Wrel2, brel2, Wroot2, hr, hro, N);
    gather2<<<2048, 256, 0, stream>>>(hr, hro, csr, base, deg, out, N);
}

// Round 10
// 252.228 us; speedup vs baseline: 1.7510x; 1.3237x over previous
//
#include <hip/hip_runtime.h>
#include <hip/hip_bf16.h>

// GraphConv x2 via dst-sorted CSR gather (no float atomics):
//   gather1:    aggm = mean_e w*x[src]
//   node_fused: lane=node, wave-uniform scalar weight loads, LDS act tile
//               read column-wise at stride 65 (2-way bank = free):
//               h   = sigmoid(aggm@Wrel1^T + b1 + x@Wroot1^T)  (h stays in LDS)
//               [hr|hro] = h@[Wrel2;Wroot2]^T (+b2 on hro)
//   gather2:    out = mean_e w*hr[src] + hro
// Round 3-9 lesson: lane=feature puts weight rows in per-lane scattered
// gathers (L1-bound, compiler remats); lane=node makes weights UNIFORM
// (scalar cache) and activations LDS-column reads (conflict-free at 65).

#define NF 64

// ---------------- dtype detection (int64 vs int32 edge_index) ---------------
__global__ void detect_i64(const unsigned* __restrict__ raw, int* __restrict__ flag, int E) {
    __shared__ unsigned red[256];
    unsigned v = 0;
    int lim = (E < 4096) ? E : 4096;
    for (int i = threadIdx.x; i < lim; i += 256) v |= raw[2 * i + 1];
    red[threadIdx.x] = v;
    __syncthreads();
    for (int s = 128; s > 0; s >>= 1) {
        if (threadIdx.x < s) red[threadIdx.x] |= red[threadIdx.x + s];
        __syncthreads();
    }
    if (threadIdx.x == 0) *flag = (red[0] == 0) ? 1 : 0;  // high dwords zero => int64
}

// ---------------- histogram of dst + materialize dst32 -----------------------
__global__ __launch_bounds__(256) void hist(const void* __restrict__ raw,
                                            const int* __restrict__ flag,
                                            int* __restrict__ deg,
                                            int* __restrict__ dst32, int E) {
    int e = blockIdx.x * blockDim.x + threadIdx.x;
    if (e >= E) return;
    int d;
    if (*flag) d = (int)__builtin_nontemporal_load(((const long long*)raw) + E + e);
    else       d = __builtin_nontemporal_load(((const int*)raw) + E + e);
    dst32[e] = d;
    atomicAdd(&deg[d], 1);
}

// ---------------- exclusive scan (3 kernels) ---------------------------------
__global__ __launch_bounds__(1024) void scan_k1(const int* __restrict__ deg,
                                                int* __restrict__ base,
                                                int* __restrict__ bsums, int N) {
    __shared__ int tmp[1024];
    int tid = threadIdx.x;
    int i = blockIdx.x * 1024 + tid;
    int v = (i < N) ? deg[i] : 0;
    tmp[tid] = v;
    __syncthreads();
    for (int off = 1; off < 1024; off <<= 1) {
        int t = (tid >= off) ? tmp[tid - off] : 0;
        __syncthreads();
        tmp[tid] += t;
        __syncthreads();
    }
    if (i < N) base[i] = tmp[tid] - v;
    if (tid == 1023) bsums[blockIdx.x] = tmp[tid];
}

__global__ __launch_bounds__(256) void scan_k2(int* __restrict__ bsums, int nb) {
    __shared__ int tmp[256];
    int tid = threadIdx.x;
    int v = (tid < nb) ? bsums[tid] : 0;
    tmp[tid] = v;
    __syncthreads();
    for (int off = 1; off < 256; off <<= 1) {
        int t = (tid >= off) ? tmp[tid - off] : 0;
        __syncthreads();
        tmp[tid] += t;
        __syncthreads();
    }
    if (tid < nb) bsums[tid] = tmp[tid] - v;
}

__global__ __launch_bounds__(1024) void scan_k3(int* __restrict__ base,
                                                const int* __restrict__ bsums,
                                                int* __restrict__ cursor, int N) {
    int i = blockIdx.x * 1024 + threadIdx.x;
    if (i >= N) return;
    int b = base[i] + bsums[blockIdx.x];
    base[i] = b;
    cursor[i] = b;
}

// ---------------- weight prep: transpose into [k][f] layouts -----------------
__global__ __launch_bounds__(256) void wprep(
    const float* __restrict__ Wrel1, const float* __restrict__ Wroot1,
    const float* __restrict__ Wrel2, const float* __restrict__ Wroot2,
    float* __restrict__ W1relT, float* __restrict__ W1rootT,
    float* __restrict__ W2T) {
    int t = threadIdx.x;
    for (int i = t; i < 4096; i += 256) {
        int f = i >> 6, k = i & 63;
        W1relT[k * 64 + f]  = Wrel1[f * 64 + k];
        W1rootT[k * 64 + f] = Wroot1[f * 64 + k];
        W2T[k * 64 + f] = (f < 32) ? Wrel2[f * 64 + k] : Wroot2[(f - 32) * 64 + k];
    }
}

// ---------------- fill CSR slots (single pass, reads cached dst32) -----------
__global__ __launch_bounds__(256) void fill_csr(const void* __restrict__ raw,
                                                const int* __restrict__ flag,
                                                const float* __restrict__ ea,
                                                const int* __restrict__ dst32,
                                                int* __restrict__ cursor,
                                                int2* __restrict__ csr, int E) {
    int e = blockIdx.x * blockDim.x + threadIdx.x;
    if (e >= E) return;
    int d = dst32[e];
    int s;
    if (*flag) s = (int)__builtin_nontemporal_load(((const long long*)raw) + e);
    else       s = __builtin_nontemporal_load(((const int*)raw) + e);
    float w = __builtin_nontemporal_load(ea + e);
    int slot = atomicAdd(&cursor[d], 1);
    csr[slot] = make_int2(s, __float_as_int(w));
}

// ---------------- gather1: aggm[n] = (sum_e w*x[src])/max(deg,1) -------------
__global__ __launch_bounds__(256) void gather1(
    const float* __restrict__ x, const int2* __restrict__ csr,
    const int* __restrict__ base, const int* __restrict__ deg,
    float* __restrict__ aggm, int N)
{
    int lane = threadIdx.x & 63;
    int wid = blockIdx.x * 4 + (threadIdx.x >> 6);
    int stride = gridDim.x * 4;
    for (int n = wid; n < N; n += stride) {
        int b = __builtin_amdgcn_readfirstlane(base[n]);
        int dg = __builtin_amdgcn_readfirstlane(deg[n]);
        float acc0 = 0.f, acc1 = 0.f, acc2 = 0.f, acc3 = 0.f;
        int i = b, e = b + dg;
        for (; i + 8 <= e; i += 8) {
            int2 r0 = csr[i], r1 = csr[i + 1], r2 = csr[i + 2], r3 = csr[i + 3];
            int2 r4 = csr[i + 4], r5 = csr[i + 5], r6 = csr[i + 6], r7 = csr[i + 7];
            float v0 = x[(size_t)r0.x * 64 + lane];
            float v1 = x[(size_t)r1.x * 64 + lane];
            float v2 = x[(size_t)r2.x * 64 + lane];
            float v3 = x[(size_t)r3.x * 64 + lane];
            float v4 = x[(size_t)r4.x * 64 + lane];
            float v5 = x[(size_t)r5.x * 64 + lane];
            float v6 = x[(size_t)r6.x * 64 + lane];
            float v7 = x[(size_t)r7.x * 64 + lane];
            acc0 = fmaf(__int_as_float(r0.y), v0, acc0);
            acc1 = fmaf(__int_as_float(r1.y), v1, acc1);
            acc2 = fmaf(__int_as_float(r2.y), v2, acc2);
            acc3 = fmaf(__int_as_float(r3.y), v3, acc3);
            acc0 = fmaf(__int_as_float(r4.y), v4, acc0);
            acc1 = fmaf(__int_as_float(r5.y), v5, acc1);
            acc2 = fmaf(__int_as_float(r6.y), v6, acc2);
            acc3 = fmaf(__int_as_float(r7.y), v7, acc3);
        }
        for (; i + 4 <= e; i += 4) {
            int2 r0 = csr[i], r1 = csr[i + 1], r2 = csr[i + 2], r3 = csr[i + 3];
            acc0 = fmaf(__int_as_float(r0.y), x[(size_t)r0.x * 64 + lane], acc0);
            acc1 = fmaf(__int_as_float(r1.y), x[(size_t)r1.x * 64 + lane], acc1);
            acc2 = fmaf(__int_as_float(r2.y), x[(size_t)r2.x * 64 + lane], acc2);
            acc3 = fmaf(__int_as_float(r3.y), x[(size_t)r3.x * 64 + lane], acc3);
        }
        for (; i < e; ++i) {
            int2 r = csr[i];
            acc0 = fmaf(__int_as_float(r.y), x[(size_t)r.x * 64 + lane], acc0);
        }
        float inv = 1.0f / fmaxf((float)dg, 1.0f);
        aggm[(size_t)n * 64 + lane] = ((acc0 + acc1) + (acc2 + acc3)) * inv;
    }
}

// ---------------- node_fused v2: lane=node, scalar weights -------------------
// Block = 64 nodes; wave w owns features [w*16, w*16+16). Act tile in LDS
// [64][65]; column read A[lane*65+k] -> banks (lane+k)%32 = 2-way = free.
// Weight rows W_T[k][fbase..fbase+15] are wave-uniform -> s_load (scalar
// cache, no vector-L1 traffic). Per k: 1 ds_read_b32 + 16 FMA -> VALU-bound.
__global__ __launch_bounds__(256) void node_fused(
    const float* __restrict__ x, const float* __restrict__ aggm,
    const float* __restrict__ W1relT, const float* __restrict__ brel1,
    const float* __restrict__ W1rootT, const float* __restrict__ W2T,
    const float* __restrict__ brel2,
    float* __restrict__ hr, float* __restrict__ hro, int N)
{
    __shared__ float A[64 * 65];
    int t = threadIdx.x;
    int lane = t & 63;
    int fbase = __builtin_amdgcn_readfirstlane((t >> 6) * 16);
    int n0 = blockIdx.x * 64;
    int rem = N - n0; if (rem > 64) rem = 64;

#define STAGE(SRC)                                                          \
    for (int idx = t; idx < 1024; idx += 256) {                             \
        int m = idx >> 4, c = idx & 15;                                     \
        int srcn = n0 + ((m < rem) ? m : 0);                                \
        float4 v = *(const float4*)((SRC) + (size_t)srcn * 64 + c * 4);     \
        float* dst = &A[m * 65 + c * 4];                                    \
        dst[0] = v.x; dst[1] = v.y; dst[2] = v.z; dst[3] = v.w;             \
    }

#define PHASE(WT_)                                                          \
    _Pragma("unroll 4")                                                     \
    for (int k = 0; k < 64; ++k) {                                          \
        float a = A[lane * 65 + k];                                         \
        const float* wk = (WT_) + k * 64 + fbase;                           \
        float4 w0 = *(const float4*)(wk);                                   \
        float4 w1 = *(const float4*)(wk + 4);                               \
        float4 w2 = *(const float4*)(wk + 8);                               \
        float4 w3 = *(const float4*)(wk + 12);                              \
        acc0.x = fmaf(a, w0.x, acc0.x); acc0.y = fmaf(a, w0.y, acc0.y);     \
        acc0.z = fmaf(a, w0.z, acc0.z); acc0.w = fmaf(a, w0.w, acc0.w);     \
        acc1.x = fmaf(a, w1.x, acc1.x); acc1.y = fmaf(a, w1.y, acc1.y);     \
        acc1.z = fmaf(a, w1.z, acc1.z); acc1.w = fmaf(a, w1.w, acc1.w);     \
        acc2.x = fmaf(a, w2.x, acc2.x); acc2.y = fmaf(a, w2.y, acc2.y);     \
        acc2.z = fmaf(a, w2.z, acc2.z); acc2.w = fmaf(a, w2.w, acc2.w);     \
        acc3.x = fmaf(a, w3.x, acc3.x); acc3.y = fmaf(a, w3.y, acc3.y);     \
        acc3.z = fmaf(a, w3.z, acc3.z); acc3.w = fmaf(a, w3.w, acc3.w);     \
    }

    // ---- phase 1: acc = b1 + aggm @ Wrel1^T (f-slice) ----
    STAGE(aggm)
    float4 acc0 = *(const float4*)(brel1 + fbase);
    float4 acc1 = *(const float4*)(brel1 + fbase + 4);
    float4 acc2 = *(const float4*)(brel1 + fbase + 8);
    float4 acc3 = *(const float4*)(brel1 + fbase + 12);
    __syncthreads();
    PHASE(W1relT)
    __syncthreads();          // phase-1 reads done before overwrite

    // ---- phase 2: acc += x @ Wroot1^T ; h = sigmoid(acc) ----
    STAGE(x)
    __syncthreads();
    PHASE(W1rootT)
    acc0.x = 1.f / (1.f + __expf(-acc0.x)); acc0.y = 1.f / (1.f + __expf(-acc0.y));
    acc0.z = 1.f / (1.f + __expf(-acc0.z)); acc0.w = 1.f / (1.f + __expf(-acc0.w));
    acc1.x = 1.f / (1.f + __expf(-acc1.x)); acc1.y = 1.f / (1.f + __expf(-acc1.y));
    acc1.z = 1.f / (1.f + __expf(-acc1.z)); acc1.w = 1.f / (1.f + __expf(-acc1.w));
    acc2.x = 1.f / (1.f + __expf(-acc2.x)); acc2.y = 1.f / (1.f + __expf(-acc2.y));
    acc2.z = 1.f / (1.f + __expf(-acc2.z)); acc2.w = 1.f / (1.f + __expf(-acc2.w));
    acc3.x = 1.f / (1.f + __expf(-acc3.x)); acc3.y = 1.f / (1.f + __expf(-acc3.y));
    acc3.z = 1.f / (1.f + __expf(-acc3.z)); acc3.w = 1.f / (1.f + __expf(-acc3.w));
    __syncthreads();          // phase-2 reads done

    // ---- h -> LDS tile (banks (lane+f)%32, 2-way) ----
    {
        float* hrow = &A[lane * 65 + fbase];
        hrow[0] = acc0.x; hrow[1] = acc0.y; hrow[2] = acc0.z; hrow[3] = acc0.w;
        hrow[4] = acc1.x; hrow[5] = acc1.y; hrow[6] = acc1.z; hrow[7] = acc1.w;
        hrow[8] = acc2.x; hrow[9] = acc2.y; hrow[10] = acc2.z; hrow[11] = acc2.w;
        hrow[12] = acc3.x; hrow[13] = acc3.y; hrow[14] = acc3.z; hrow[15] = acc3.w;
    }
    __syncthreads();

    // ---- phase 3: out2[j-slice] = h @ W2T (+b2 for j>=32) ----
    if (fbase < 32) {
        acc0 = make_float4(0.f, 0.f, 0.f, 0.f);
        acc1 = acc0; acc2 = acc0; acc3 = acc0;
    } else {
        acc0 = *(const float4*)(brel2 + fbase - 32);
        acc1 = *(const float4*)(brel2 + fbase - 28);
        acc2 = *(const float4*)(brel2 + fbase - 24);
        acc3 = *(const float4*)(brel2 + fbase - 20);
    }
    PHASE(W2T)
    __syncthreads();          // phase-3 reads done

    // ---- out2 -> LDS, then coalesced global write ----
    {
        float* orow = &A[lane * 65 + fbase];
        orow[0] = acc0.x; orow[1] = acc0.y; orow[2] = acc0.z; orow[3] = acc0.w;
        orow[4] = acc1.x; orow[5] = acc1.y; orow[6] = acc1.z; orow[7] = acc1.w;
        orow[8] = acc2.x; orow[9] = acc2.y; orow[10] = acc2.z; orow[11] = acc2.w;
        orow[12] = acc3.x; orow[13] = acc3.y; orow[14] = acc3.z; orow[15] = acc3.w;
    }
    __syncthreads();
    for (int idx = t; idx < 1024; idx += 256) {
        int m = idx >> 4, c = idx & 15;
        if (m < rem) {
            const float* src = &A[m * 65 + c * 4];
            float4 v = make_float4(src[0], src[1], src[2], src[3]);
            if (c < 8) *(float4*)(hr + (size_t)(n0 + m) * 32 + c * 4) = v;
            else       *(float4*)(hro + (size_t)(n0 + m) * 32 + (c - 8) * 4) = v;
        }
    }
#undef STAGE
#undef PHASE
}

// ---------------- gather2 + epilogue: out = agg2/deg + hro -------------------
__global__ __launch_bounds__(256) void gather2(
    const float* __restrict__ hr, const float* __restrict__ hro,
    const int2* __restrict__ csr, const int* __restrict__ base,
    const int* __restrict__ deg, float* __restrict__ out, int N)
{
    int lane = threadIdx.x & 63;
    int j = lane & 31, half = lane >> 5;
    int wid = blockIdx.x * 4 + (threadIdx.x >> 6);
    int stride = gridDim.x * 4;
    for (int n = wid; n < N; n += stride) {
        int b = __builtin_amdgcn_readfirstlane(base[n]);
        int dg = __builtin_amdgcn_readfirstlane(deg[n]);
        float a0 = 0.f, a1 = 0.f, a2 = 0.f, a3 = 0.f;
        int i = b + half, e = b + dg;
        for (; i + 8 <= e + half; i += 8) {
            int2 r0 = csr[i], r1 = csr[i + 2], r2 = csr[i + 4], r3 = csr[i + 6];
            a0 = fmaf(__int_as_float(r0.y), hr[(size_t)r0.x * 32 + j], a0);
            a1 = fmaf(__int_as_float(r1.y), hr[(size_t)r1.x * 32 + j], a1);
            a2 = fmaf(__int_as_float(r2.y), hr[(size_t)r2.x * 32 + j], a2);
            a3 = fmaf(__int_as_float(r3.y), hr[(size_t)r3.x * 32 + j], a3);
        }
        for (; i < e; i += 2) {
            int2 r = csr[i];
            a0 = fmaf(__int_as_float(r.y), hr[(size_t)r.x * 32 + j], a0);
        }
        float acc = (a0 + a1) + (a2 + a3);
        acc += __shfl_xor(acc, 32);
        if (half == 0) {
            float inv = 1.0f / fmaxf((float)dg, 1.0f);
            out[(size_t)n * 32 + j] = acc * inv + hro[(size_t)n * 32 + j];
        }
    }
}

extern "C" void kernel_launch(void* const* d_in, const int* in_sizes, int n_in,
                              void* d_out, int out_size, void* d_ws, size_t ws_size,
                              hipStream_t stream) {
    const float* x      = (const float*)d_in[0];
    const void*  ei_raw = d_in[1];
    const float* ea     = (const float*)d_in[2];
    const float* Wrel1  = (const float*)d_in[3];
    const float* brel1  = (const float*)d_in[4];
    const float* Wroot1 = (const float*)d_in[5];
    const float* Wrel2  = (const float*)d_in[6];
    const float* brel2  = (const float*)d_in[7];
    const float* Wroot2 = (const float*)d_in[8];
    float* out = (float*)d_out;

    const int N = in_sizes[0] / NF;     // 100000
    const int E = in_sizes[2];          // 1000000

    // workspace layout
    int2*  csr     = (int2*)d_ws;                   // E (8 MB)
    int*   deg     = (int*)(csr + E);               // N
    int*   base    = deg + N;                       // N
    int*   cursor  = base + N;                      // N
    int*   bsums   = cursor + N;                    // 256
    int*   flag    = bsums + 256;                   // 1 (+3 pad)
    int*   dst32   = flag + 4;                      // E (4 MB)
    float* aggm    = (float*)(dst32 + E);           // N*64
    float* hr      = aggm + (size_t)N * 64;         // N*32
    float* hro     = hr + (size_t)N * 32;           // N*32
    float* W1relT  = hro + (size_t)N * 32;          // 4096
    float* W1rootT = W1relT + 4096;                 // 4096
    float* W2T     = W1rootT + 4096;                // 4096

    const int nb1 = (N + 1023) / 1024;

    hipMemsetAsync(deg, 0, (size_t)N * sizeof(int), stream);
    detect_i64<<<1, 256, 0, stream>>>((const unsigned*)ei_raw, flag, E);
    wprep<<<1, 256, 0, stream>>>(Wrel1, Wroot1, Wrel2, Wroot2, W1relT, W1rootT, W2T);
    hist<<<(E + 255) / 256, 256, 0, stream>>>(ei_raw, flag, deg, dst32, E);
    scan_k1<<<nb1, 1024, 0, stream>>>(deg, base, bsums, N);
    scan_k2<<<1, 256, 0, stream>>>(bsums, nb1);
    scan_k3<<<nb1, 1024, 0, stream>>>(base, bsums, cursor, N);
    fill_csr<<<(E + 255) / 256, 256, 0, stream>>>(ei_raw, flag, ea, dst32, cursor, csr, E);

    gather1<<<2048, 256, 0, stream>>>(x, csr, base, deg, aggm, N);
    node_fused<<<(N + 63) / 64, 256, 0, stream>>>(x, aggm, W1relT, brel1, W1rootT,
                                                  W2T, brel2, hr, hro, N);
    gather2<<<2048, 256, 0, stream>>>(hr, hro, csr, base, deg, out, N);
}

// Round 11
// 227.565 us; speedup vs baseline: 1.9408x; 1.1084x over previous
//
#include <hip/hip_runtime.h>
#include <hip/hip_bf16.h>

// GraphConv x2 via dst-sorted CSR gather (no float atomics):
//   gather1:    aggm = mean_e w*x[src]
//   node_fused: lane=node, wave-uniform scalar weight loads, LDS act tile
//               read column-wise at stride 65 (2-way bank = free)
//   gather2:    out = mean_e w*hr[src] + hro
// CSR build: hist assigns rank[e] = atomicAdd(deg[d],1) (rank is free with
// the histogram atomic); fill_csr is then ATOMIC-FREE: slot = base[d]+rank[e],
// nontemporal 8B scatter with no dependency chain.

#define NF 64

// ---------------- dtype detection (int64 vs int32 edge_index) ---------------
__global__ void detect_i64(const unsigned* __restrict__ raw, int* __restrict__ flag, int E) {
    __shared__ unsigned red[256];
    unsigned v = 0;
    int lim = (E < 4096) ? E : 4096;
    for (int i = threadIdx.x; i < lim; i += 256) v |= raw[2 * i + 1];
    red[threadIdx.x] = v;
    __syncthreads();
    for (int s = 128; s > 0; s >>= 1) {
        if (threadIdx.x < s) red[threadIdx.x] |= red[threadIdx.x + s];
        __syncthreads();
    }
    if (threadIdx.x == 0) *flag = (red[0] == 0) ? 1 : 0;  // high dwords zero => int64
}

// ------- histogram of dst + materialize dst32 + per-dst rank (free) ---------
__global__ __launch_bounds__(256) void hist(const void* __restrict__ raw,
                                            const int* __restrict__ flag,
                                            int* __restrict__ deg,
                                            int* __restrict__ dst32,
                                            int* __restrict__ rank32, int E) {
    int e = blockIdx.x * blockDim.x + threadIdx.x;
    if (e >= E) return;
    int d;
    if (*flag) d = (int)__builtin_nontemporal_load(((const long long*)raw) + E + e);
    else       d = __builtin_nontemporal_load(((const int*)raw) + E + e);
    dst32[e] = d;
    rank32[e] = atomicAdd(&deg[d], 1);
}

// ---------------- exclusive scan (3 kernels) ---------------------------------
__global__ __launch_bounds__(1024) void scan_k1(const int* __restrict__ deg,
                                                int* __restrict__ base,
                                                int* __restrict__ bsums, int N) {
    __shared__ int tmp[1024];
    int tid = threadIdx.x;
    int i = blockIdx.x * 1024 + tid;
    int v = (i < N) ? deg[i] : 0;
    tmp[tid] = v;
    __syncthreads();
    for (int off = 1; off < 1024; off <<= 1) {
        int t = (tid >= off) ? tmp[tid - off] : 0;
        __syncthreads();
        tmp[tid] += t;
        __syncthreads();
    }
    if (i < N) base[i] = tmp[tid] - v;
    if (tid == 1023) bsums[blockIdx.x] = tmp[tid];
}

__global__ __launch_bounds__(256) void scan_k2(int* __restrict__ bsums, int nb) {
    __shared__ int tmp[256];
    int tid = threadIdx.x;
    int v = (tid < nb) ? bsums[tid] : 0;
    tmp[tid] = v;
    __syncthreads();
    for (int off = 1; off < 256; off <<= 1) {
        int t = (tid >= off) ? tmp[tid - off] : 0;
        __syncthreads();
        tmp[tid] += t;
        __syncthreads();
    }
    if (tid < nb) bsums[tid] = tmp[tid] - v;
}

__global__ __launch_bounds__(1024) void scan_k3(int* __restrict__ base,
                                                const int* __restrict__ bsums, int N) {
    int i = blockIdx.x * 1024 + threadIdx.x;
    if (i >= N) return;
    base[i] += bsums[blockIdx.x];
}

// ---------------- weight prep: transpose into [k][f] layouts -----------------
__global__ __launch_bounds__(256) void wprep(
    const float* __restrict__ Wrel1, const float* __restrict__ Wroot1,
    const float* __restrict__ Wrel2, const float* __restrict__ Wroot2,
    float* __restrict__ W1relT, float* __restrict__ W1rootT,
    float* __restrict__ W2T) {
    int t = threadIdx.x;
    for (int i = t; i < 4096; i += 256) {
        int f = i >> 6, k = i & 63;
        W1relT[k * 64 + f]  = Wrel1[f * 64 + k];
        W1rootT[k * 64 + f] = Wroot1[f * 64 + k];
        W2T[k * 64 + f] = (f < 32) ? Wrel2[f * 64 + k] : Wroot2[(f - 32) * 64 + k];
    }
}

// ---------------- fill CSR slots: ATOMIC-FREE scatter ------------------------
__global__ __launch_bounds__(256) void fill_csr(const void* __restrict__ raw,
                                                const int* __restrict__ flag,
                                                const float* __restrict__ ea,
                                                const int* __restrict__ dst32,
                                                const int* __restrict__ rank32,
                                                const int* __restrict__ base,
                                                long long* __restrict__ csr, int E) {
    int e = blockIdx.x * blockDim.x + threadIdx.x;
    if (e >= E) return;
    int d = dst32[e];
    int s;
    if (*flag) s = (int)__builtin_nontemporal_load(((const long long*)raw) + e);
    else       s = __builtin_nontemporal_load(((const int*)raw) + e);
    float w = __builtin_nontemporal_load(ea + e);
    int slot = base[d] + rank32[e];
    long long packed = (unsigned int)s | ((long long)__float_as_int(w) << 32);
    __builtin_nontemporal_store(packed, csr + slot);
}

// ---------------- gather1: aggm[n] = (sum_e w*x[src])/max(deg,1) -------------
__global__ __launch_bounds__(256) void gather1(
    const float* __restrict__ x, const int2* __restrict__ csr,
    const int* __restrict__ base, const int* __restrict__ deg,
    float* __restrict__ aggm, int N)
{
    int lane = threadIdx.x & 63;
    int wid = blockIdx.x * 4 + (threadIdx.x >> 6);
    int stride = gridDim.x * 4;
    for (int n = wid; n < N; n += stride) {
        int b = __builtin_amdgcn_readfirstlane(base[n]);
        int dg = __builtin_amdgcn_readfirstlane(deg[n]);
        float acc0 = 0.f, acc1 = 0.f, acc2 = 0.f, acc3 = 0.f;
        int i = b, e = b + dg;
        for (; i + 8 <= e; i += 8) {
            int2 r0 = csr[i], r1 = csr[i + 1], r2 = csr[i + 2], r3 = csr[i + 3];
            int2 r4 = csr[i + 4], r5 = csr[i + 5], r6 = csr[i + 6], r7 = csr[i + 7];
            float v0 = x[(size_t)r0.x * 64 + lane];
            float v1 = x[(size_t)r1.x * 64 + lane];
            float v2 = x[(size_t)r2.x * 64 + lane];
            float v3 = x[(size_t)r3.x * 64 + lane];
            float v4 = x[(size_t)r4.x * 64 + lane];
            float v5 = x[(size_t)r5.x * 64 + lane];
            float v6 = x[(size_t)r6.x * 64 + lane];
            float v7 = x[(size_t)r7.x * 64 + lane];
            acc0 = fmaf(__int_as_float(r0.y), v0, acc0);
            acc1 = fmaf(__int_as_float(r1.y), v1, acc1);
            acc2 = fmaf(__int_as_float(r2.y), v2, acc2);
            acc3 = fmaf(__int_as_float(r3.y), v3, acc3);
            acc0 = fmaf(__int_as_float(r4.y), v4, acc0);
            acc1 = fmaf(__int_as_float(r5.y), v5, acc1);
            acc2 = fmaf(__int_as_float(r6.y), v6, acc2);
            acc3 = fmaf(__int_as_float(r7.y), v7, acc3);
        }
        for (; i + 4 <= e; i += 4) {
            int2 r0 = csr[i], r1 = csr[i + 1], r2 = csr[i + 2], r3 = csr[i + 3];
            acc0 = fmaf(__int_as_float(r0.y), x[(size_t)r0.x * 64 + lane], acc0);
            acc1 = fmaf(__int_as_float(r1.y), x[(size_t)r1.x * 64 + lane], acc1);
            acc2 = fmaf(__int_as_float(r2.y), x[(size_t)r2.x * 64 + lane], acc2);
            acc3 = fmaf(__int_as_float(r3.y), x[(size_t)r3.x * 64 + lane], acc3);
        }
        for (; i < e; ++i) {
            int2 r = csr[i];
            acc0 = fmaf(__int_as_float(r.y), x[(size_t)r.x * 64 + lane], acc0);
        }
        float inv = 1.0f / fmaxf((float)dg, 1.0f);
        aggm[(size_t)n * 64 + lane] = ((acc0 + acc1) + (acc2 + acc3)) * inv;
    }
}

// ---------------- node_fused v2: lane=node, scalar weights -------------------
__global__ __launch_bounds__(256) void node_fused(
    const float* __restrict__ x, const float* __restrict__ aggm,
    const float* __restrict__ W1relT, const float* __restrict__ brel1,
    const float* __restrict__ W1rootT, const float* __restrict__ W2T,
    const float* __restrict__ brel2,
    float* __restrict__ hr, float* __restrict__ hro, int N)
{
    __shared__ float A[64 * 65];
    int t = threadIdx.x;
    int lane = t & 63;
    int fbase = __builtin_amdgcn_readfirstlane((t >> 6) * 16);
    int n0 = blockIdx.x * 64;
    int rem = N - n0; if (rem > 64) rem = 64;

#define STAGE(SRC)                                                          \
    for (int idx = t; idx < 1024; idx += 256) {                             \
        int m = idx >> 4, c = idx & 15;                                     \
        int srcn = n0 + ((m < rem) ? m : 0);                                \
        float4 v = *(const float4*)((SRC) + (size_t)srcn * 64 + c * 4);     \
        float* dst = &A[m * 65 + c * 4];                                    \
        dst[0] = v.x; dst[1] = v.y; dst[2] = v.z; dst[3] = v.w;             \
    }

#define PHASE(WT_)                                                          \
    _Pragma("unroll 4")                                                     \
    for (int k = 0; k < 64; ++k) {                                          \
        float a = A[lane * 65 + k];                                         \
        const float* wk = (WT_) + k * 64 + fbase;                           \
        float4 w0 = *(const float4*)(wk);                                   \
        float4 w1 = *(const float4*)(wk + 4);                               \
        float4 w2 = *(const float4*)(wk + 8);                               \
        float4 w3 = *(const float4*)(wk + 12);                              \
        acc0.x = fmaf(a, w0.x, acc0.x); acc0.y = fmaf(a, w0.y, acc0.y);     \
        acc0.z = fmaf(a, w0.z, acc0.z); acc0.w = fmaf(a, w0.w, acc0.w);     \
        acc1.x = fmaf(a, w1.x, acc1.x); acc1.y = fmaf(a, w1.y, acc1.y);     \
        acc1.z = fmaf(a, w1.z, acc1.z); acc1.w = fmaf(a, w1.w, acc1.w);     \
        acc2.x = fmaf(a, w2.x, acc2.x); acc2.y = fmaf(a, w2.y, acc2.y);     \
        acc2.z = fmaf(a, w2.z, acc2.z); acc2.w = fmaf(a, w2.w, acc2.w);     \
        acc3.x = fmaf(a, w3.x, acc3.x); acc3.y = fmaf(a, w3.y, acc3.y);     \
        acc3.z = fmaf(a, w3.z, acc3.z); acc3.w = fmaf(a, w3.w, acc3.w);     \
    }

    // ---- phase 1: acc = b1 + aggm @ Wrel1^T (f-slice) ----
    STAGE(aggm)
    float4 acc0 = *(const float4*)(brel1 + fbase);
    float4 acc1 = *(const float4*)(brel1 + fbase + 4);
    float4 acc2 = *(const float4*)(brel1 + fbase + 8);
    float4 acc3 = *(const float4*)(brel1 + fbase + 12);
    __syncthreads();
    PHASE(W1relT)
    __syncthreads();

    // ---- phase 2: acc += x @ Wroot1^T ; h = sigmoid(acc) ----
    STAGE(x)
    __syncthreads();
    PHASE(W1rootT)
    acc0.x = 1.f / (1.f + __expf(-acc0.x)); acc0.y = 1.f / (1.f + __expf(-acc0.y));
    acc0.z = 1.f / (1.f + __expf(-acc0.z)); acc0.w = 1.f / (1.f + __expf(-acc0.w));
    acc1.x = 1.f / (1.f + __expf(-acc1.x)); acc1.y = 1.f / (1.f + __expf(-acc1.y));
    acc1.z = 1.f / (1.f + __expf(-acc1.z)); acc1.w = 1.f / (1.f + __expf(-acc1.w));
    acc2.x = 1.f / (1.f + __expf(-acc2.x)); acc2.y = 1.f / (1.f + __expf(-acc2.y));
    acc2.z = 1.f / (1.f + __expf(-acc2.z)); acc2.w = 1.f / (1.f + __expf(-acc2.w));
    acc3.x = 1.f / (1.f + __expf(-acc3.x)); acc3.y = 1.f / (1.f + __expf(-acc3.y));
    acc3.z = 1.f / (1.f + __expf(-acc3.z)); acc3.w = 1.f / (1.f + __expf(-acc3.w));
    __syncthreads();

    // ---- h -> LDS tile ----
    {
        float* hrow = &A[lane * 65 + fbase];
        hrow[0] = acc0.x; hrow[1] = acc0.y; hrow[2] = acc0.z; hrow[3] = acc0.w;
        hrow[4] = acc1.x; hrow[5] = acc1.y; hrow[6] = acc1.z; hrow[7] = acc1.w;
        hrow[8] = acc2.x; hrow[9] = acc2.y; hrow[10] = acc2.z; hrow[11] = acc2.w;
        hrow[12] = acc3.x; hrow[13] = acc3.y; hrow[14] = acc3.z; hrow[15] = acc3.w;
    }
    __syncthreads();

    // ---- phase 3: out2[j-slice] = h @ W2T (+b2 for j>=32) ----
    if (fbase < 32) {
        acc0 = make_float4(0.f, 0.f, 0.f, 0.f);
        acc1 = acc0; acc2 = acc0; acc3 = acc0;
    } else {
        acc0 = *(const float4*)(brel2 + fbase - 32);
        acc1 = *(const float4*)(brel2 + fbase - 28);
        acc2 = *(const float4*)(brel2 + fbase - 24);
        acc3 = *(const float4*)(brel2 + fbase - 20);
    }
    PHASE(W2T)
    __syncthreads();

    // ---- out2 -> LDS, then coalesced global write ----
    {
        float* orow = &A[lane * 65 + fbase];
        orow[0] = acc0.x; orow[1] = acc0.y; orow[2] = acc0.z; orow[3] = acc0.w;
        orow[4] = acc1.x; orow[5] = acc1.y; orow[6] = acc1.z; orow[7] = acc1.w;
        orow[8] = acc2.x; orow[9] = acc2.y; orow[10] = acc2.z; orow[11] = acc2.w;
        orow[12] = acc3.x; orow[13] = acc3.y; orow[14] = acc3.z; orow[15] = acc3.w;
    }
    __syncthreads();
    for (int idx = t; idx < 1024; idx += 256) {
        int m = idx >> 4, c = idx & 15;
        if (m < rem) {
            const float* src = &A[m * 65 + c * 4];
            float4 v = make_float4(src[0], src[1], src[2], src[3]);
            if (c < 8) *(float4*)(hr + (size_t)(n0 + m) * 32 + c * 4) = v;
            else       *(float4*)(hro + (size_t)(n0 + m) * 32 + (c - 8) * 4) = v;
        }
    }
#undef STAGE
#undef PHASE
}

// ---------------- gather2 + epilogue: out = agg2/deg + hro -------------------
__global__ __launch_bounds__(256) void gather2(
    const float* __restrict__ hr, const float* __restrict__ hro,
    const int2* __restrict__ csr, const int* __restrict__ base,
    const int* __restrict__ deg, float* __restrict__ out, int N)
{
    int lane = threadIdx.x & 63;
    int j = lane & 31, half = lane >> 5;
    int wid = blockIdx.x * 4 + (threadIdx.x >> 6);
    int stride = gridDim.x * 4;
    for (int n = wid; n < N; n += stride) {
        int b = __builtin_amdgcn_readfirstlane(base[n]);
        int dg = __builtin_amdgcn_readfirstlane(deg[n]);
        float a0 = 0.f, a1 = 0.f, a2 = 0.f, a3 = 0.f;
        int i = b + half, e = b + dg;
        for (; i + 8 <= e + half; i += 8) {
            int2 r0 = csr[i], r1 = csr[i + 2], r2 = csr[i + 4], r3 = csr[i + 6];
            a0 = fmaf(__int_as_float(r0.y), hr[(size_t)r0.x * 32 + j], a0);
            a1 = fmaf(__int_as_float(r1.y), hr[(size_t)r1.x * 32 + j], a1);
            a2 = fmaf(__int_as_float(r2.y), hr[(size_t)r2.x * 32 + j], a2);
            a3 = fmaf(__int_as_float(r3.y), hr[(size_t)r3.x * 32 + j], a3);
        }
        for (; i < e; i += 2) {
            int2 r = csr[i];
            a0 = fmaf(__int_as_float(r.y), hr[(size_t)r.x * 32 + j], a0);
        }
        float acc = (a0 + a1) + (a2 + a3);
        acc += __shfl_xor(acc, 32);
        if (half == 0) {
            float inv = 1.0f / fmaxf((float)dg, 1.0f);
            out[(size_t)n * 32 + j] = acc * inv + hro[(size_t)n * 32 + j];
        }
    }
}

extern "C" void kernel_launch(void* const* d_in, const int* in_sizes, int n_in,
                              void* d_out, int out_size, void* d_ws, size_t ws_size,
                              hipStream_t stream) {
    const float* x      = (const float*)d_in[0];
    const void*  ei_raw = d_in[1];
    const float* ea     = (const float*)d_in[2];
    const float* Wrel1  = (const float*)d_in[3];
    const float* brel1  = (const float*)d_in[4];
    const float* Wroot1 = (const float*)d_in[5];
    const float* Wrel2  = (const float*)d_in[6];
    const float* brel2  = (const float*)d_in[7];
    const float* Wroot2 = (const float*)d_in[8];
    float* out = (float*)d_out;

    const int N = in_sizes[0] / NF;     // 100000
    const int E = in_sizes[2];          // 1000000

    // workspace layout
    long long* csr = (long long*)d_ws;              // E (8 MB)
    int*   deg     = (int*)(csr + E);               // N
    int*   base    = deg + N;                       // N
    int*   bsums   = base + N;                      // 256
    int*   flag    = bsums + 256;                   // 1 (+3 pad)
    int*   dst32   = flag + 4;                      // E (4 MB)
    int*   rank32  = dst32 + E;                     // E (4 MB)
    float* aggm    = (float*)(rank32 + E);          // N*64
    float* hr      = aggm + (size_t)N * 64;         // N*32
    float* hro     = hr + (size_t)N * 32;           // N*32
    float* W1relT  = hro + (size_t)N * 32;          // 4096
    float* W1rootT = W1relT + 4096;                 // 4096
    float* W2T     = W1rootT + 4096;                // 4096

    const int nb1 = (N + 1023) / 1024;

    hipMemsetAsync(deg, 0, (size_t)N * sizeof(int), stream);
    detect_i64<<<1, 256, 0, stream>>>((const unsigned*)ei_raw, flag, E);
    wprep<<<1, 256, 0, stream>>>(Wrel1, Wroot1, Wrel2, Wroot2, W1relT, W1rootT, W2T);
    hist<<<(E + 255) / 256, 256, 0, stream>>>(ei_raw, flag, deg, dst32, rank32, E);
    scan_k1<<<nb1, 1024, 0, stream>>>(deg, base, bsums, N);
    scan_k2<<<1, 256, 0, stream>>>(bsums, nb1);
    scan_k3<<<nb1, 1024, 0, stream>>>(base, bsums, N);
    fill_csr<<<(E + 255) / 256, 256, 0, stream>>>(ei_raw, flag, ea, dst32, rank32,
                                                  base, csr, E);

    gather1<<<2048, 256, 0, stream>>>(x, (const int2*)csr, base, deg, aggm, N);
    node_fused<<<(N + 63) / 64, 256, 0, stream>>>(x, aggm, W1relT, brel1, W1rootT,
                                                  W2T, brel2, hr, hro, N);
    gather2<<<2048, 256, 0, stream>>>(hr, hro, (const int2*)csr, base, deg, out, N);
}